// Round 6
// baseline (331.687 us; speedup 1.0000x reference)
//
#include <hip/hip_runtime.h>
#include <hip/hip_cooperative_groups.h>

namespace cg = cooperative_groups;

#define EPS 1e-5f
#define PROJ_EPS 1e-5f
#define MAX_TANH_ARG 15.0f

typedef __bf16 bf16x8 __attribute__((ext_vector_type(8)));
typedef float f32x4 __attribute__((ext_vector_type(4)));
typedef float f32x2 __attribute__((ext_vector_type(2)));

__device__ __forceinline__ unsigned short f2bf(float f) {
  unsigned u = __builtin_bit_cast(unsigned, f);
  u += 0x7fffu + ((u >> 16) & 1u);   // round-to-nearest-even
  return (unsigned short)(u >> 16);
}

union BF8 {
  unsigned short u[8];
  bf16x8 v;
  uint4 q;
};

// Time-shared LDS: 17664 B total -> >=2 blocks/CU even under 64 KiB accounting.
struct SMem {
  union {
    unsigned short tile[64][136];        // 17408 B: gemm A-stage/C-tile, x1 tile
    unsigned long long pairs[64 * 33];   // 16896 B: (id,w) staging for gathers
  };
  float lsb[64];
};

// ---------------- phase 0: pack W[layer][k][n] -> bf16 B-frag order ---------
__device__ __forceinline__ void do_pack(const float* __restrict__ W,
                                        unsigned short* __restrict__ wpack,
                                        int tid) {
  if (tid >= 2 * 8 * 4 * 64) return;
  const int l = tid & 63;
  const int s = (tid >> 6) & 3;
  const int tt = (tid >> 8) & 7;
  const int layer = tid >> 11;
  const int q2 = l >> 4;
  const int n = tt * 16 + (l & 15);
  unsigned short* dst = wpack + ((size_t)((layer * 32 + tt * 4 + s) * 64 + l)) * 8;
  const float* src = W + (size_t)layer * 16384;
#pragma unroll
  for (int j = 0; j < 8; ++j) {
    const int k = s * 32 + q2 * 8 + j;
    dst[j] = f2bf(src[(size_t)k * 128 + n]);
  }
}

// ---------------- phase 1: msg1 = mask^2 * (node @ W0), plane-tiled ---------
// All LDS traffic is wave-local (same-wave DS ops are in-order) -> no barriers.
__device__ __forceinline__ void do_gemm0(SMem& sm, const float* __restrict__ xf,
                                         const float* __restrict__ mask,
                                         const unsigned short* __restrict__ wpack,
                                         unsigned short* __restrict__ msg1,
                                         int N, int planeBytes, int tb) {
  const int t = threadIdx.x;
  const int lane = t & 63;
  const int wv = t >> 6;
  const int m = lane & 15;
  const int quad = lane >> 4;
  const int wbase = tb * 64 + wv * 16;

  {  // coalesced fp32 load -> bf16 stage into own wave's 16 tile rows
    const int r = lane >> 2;
    const int c = (lane & 3) * 32;
    const int gr = wbase + r;
    const int grc = gr < N ? gr : N - 1;
    const float4* src = (const float4*)(xf + (size_t)grc * 128 + c);
    unsigned short* drow = &sm.tile[wv * 16 + r][c];
#pragma unroll
    for (int i = 0; i < 8; ++i) {
      const float4 p = src[i];
      drow[i * 4 + 0] = f2bf(p.x);
      drow[i * 4 + 1] = f2bf(p.y);
      drow[i * 4 + 2] = f2bf(p.z);
      drow[i * 4 + 3] = f2bf(p.w);
    }
  }

  f32x4 acc[8];
#pragma unroll
  for (int tt = 0; tt < 8; ++tt) acc[tt] = (f32x4){0.f, 0.f, 0.f, 0.f};
#pragma unroll
  for (int sk = 0; sk < 4; ++sk) {
    BF8 a;
    a.q = *(const uint4*)&sm.tile[wv * 16 + m][sk * 32 + quad * 8];
#pragma unroll
    for (int tt = 0; tt < 8; ++tt) {
      BF8 b;
      b.q = *(const uint4*)(wpack + (size_t)((tt * 4 + sk) * 64 + lane) * 8);
      acc[tt] = __builtin_amdgcn_mfma_f32_16x16x32_bf16(a.v, b.v, acc[tt], 0, 0, 0);
    }
  }

  float sc[4];
#pragma unroll
  for (int r = 0; r < 4; ++r) {
    int rr = wbase + quad * 4 + r;
    rr = rr < N ? rr : N - 1;
    const float s = mask[rr];
    sc[r] = s * s;
  }
  // C overwrite of own wave's rows (all A reads precede in program order)
#pragma unroll
  for (int tt = 0; tt < 8; ++tt) {
    const int c = tt * 16 + m;
#pragma unroll
    for (int r = 0; r < 4; ++r)
      sm.tile[wv * 16 + quad * 4 + r][c] = f2bf(acc[tt][r] * sc[r]);
  }
  // wave-local coalesced plane writeout
  const int r16 = lane >> 2;
  const int sub2 = lane & 3;
  const int grow = wbase + r16;
  if (grow < N) {
#pragma unroll
    for (int p = 0; p < 4; ++p) {
      *(uint4*)((char*)msg1 + (size_t)p * planeBytes + (size_t)grow * 64 + sub2 * 16) =
          *(const uint4*)((const char*)&sm.tile[wv * 16 + r16][0] + p * 64 + sub2 * 16);
    }
  }
}

// ------- shared gather core: acc[16] = sum_k w * msgP[adj], plane passes ----
__device__ __forceinline__ void gather_core(SMem& sm, const int* __restrict__ adj,
                                            const float* __restrict__ wgt,
                                            const unsigned short* __restrict__ msg,
                                            int N, int planeBytes, int nbase,
                                            f32x2 (&acc)[16]) {
  const int t = threadIdx.x;
  const int lane = t & 63;
  const int wv = t >> 6;
  for (int e = t; e < 64 * 32; e += 256) {
    const int node = e >> 5, k = e & 31;
    const int gn = nbase + node;
    int id = 0;
    float w = 0.f;
    if (gn < N) {
      id = adj[(size_t)gn * 32 + k];
      w = wgt[(size_t)gn * 32 + k];
    }
    sm.pairs[node * 33 + k] = (unsigned long long)(unsigned)id |
        ((unsigned long long)__builtin_bit_cast(unsigned, w) << 32);
  }
  __syncthreads();

  const int mynode = wv * 16 + (lane >> 2);
  const unsigned long long* mp = sm.pairs + mynode * 33;
  const int suboff = (lane & 3) * 16;
#pragma unroll
  for (int i = 0; i < 16; ++i) acc[i] = (f32x2){0.f, 0.f};
#pragma unroll
  for (int p = 0; p < 4; ++p) {
    const char* plane = (const char*)msg + (size_t)p * planeBytes;
#pragma unroll 8
    for (int k = 0; k < 32; ++k) {
      const unsigned long long pk = mp[k];
      const unsigned id = (unsigned)pk;
      const float w = __builtin_bit_cast(float, (unsigned)(pk >> 32));
      const uint4 q = *(const uint4*)(plane + ((size_t)id * 64 + suboff));
      const f32x2 w2 = {w, w};
#pragma unroll
      for (int d = 0; d < 4; ++d) {
        const unsigned qd = (&q.x)[d];
        f32x2 v2;
        v2.x = __builtin_bit_cast(float, qd << 16);
        v2.y = __builtin_bit_cast(float, qd & 0xffff0000u);
        acc[p * 4 + d] = __builtin_elementwise_fma(v2, w2, acc[p * 4 + d]);
      }
    }
  }
}

// --------- phase 2: x1 = act(gather(msg1)); msg2 = ls*(x1 @ W1) -------------
__device__ __forceinline__ void do_fused(SMem& sm, const unsigned short* __restrict__ msg1,
                                         const int* __restrict__ adj,
                                         const float* __restrict__ wgt,
                                         const float* __restrict__ mask,
                                         const unsigned short* __restrict__ wpack2,
                                         unsigned short* __restrict__ msg2,
                                         int N, int planeBytes, int nbase) {
  const int t = threadIdx.x;
  const int lane = t & 63;
  const int wv = t >> 6;
  const int m = lane & 15;
  const int quad = lane >> 4;
  const int sub = lane & 3;
  const int mynode = wv * 16 + (lane >> 2);
  const int gnode = nbase + mynode;
  const int suboff = sub * 16;

  f32x2 acc[16];
  gather_core(sm, adj, wgt, msg1, N, planeBytes, nbase, acc);

  const int gcl = gnode < N ? gnode : N - 1;
  const float mm = mask[gcl];
  float s2 = 0.f;
#pragma unroll
  for (int i = 0; i < 16; ++i) {
    acc[i].x *= mm;
    acc[i].y *= mm;
    s2 = fmaf(acc[i].x, acc[i].x, s2);
    s2 = fmaf(acc[i].y, acc[i].y, s2);
  }
  s2 += __shfl_xor(s2, 1);
  s2 += __shfl_xor(s2, 2);
  const float nrm = sqrtf(s2);
  const float ncl = fminf(fmaxf(nrm, EPS), MAX_TANH_ARG);
  const float esc = tanhf(ncl) / fmaxf(nrm, EPS) * mm;
  float v[32];
  float r2 = 0.f;
#pragma unroll
  for (int i = 0; i < 16; ++i) {
    v[2 * i] = fmaxf(esc * acc[i].x, 0.f) * mm;
    v[2 * i + 1] = fmaxf(esc * acc[i].y, 0.f) * mm;
    r2 = fmaf(v[2 * i], v[2 * i], r2);
    r2 = fmaf(v[2 * i + 1], v[2 * i + 1], r2);
  }
  r2 += __shfl_xor(r2, 1);
  r2 += __shfl_xor(r2, 2);

  __syncthreads();  // pairs dead; tile (aliasing pairs) may now be written

#pragma unroll
  for (int p = 0; p < 4; ++p) {
    uint4 pk4;
    unsigned* pw = &pk4.x;
#pragma unroll
    for (int d = 0; d < 4; ++d)
      pw[d] = (unsigned)f2bf(v[p * 8 + d * 2]) |
              ((unsigned)f2bf(v[p * 8 + d * 2 + 1]) << 16);
    *(uint4*)((char*)&sm.tile[mynode][0] + p * 64 + suboff) = pk4;
  }
  if (sub == 0) {
    const float nr = sqrtf(r2);
    const float nc2 = fminf(fmaxf(nr, EPS), 1.0f - PROJ_EPS);
    const float ls = 0.5f * logf((1.f + nc2) / (1.f - nc2)) / fmaxf(nr, EPS);
    sm.lsb[mynode] = ls * mm * mm;  // fold layer-2 mask^2
  }
  // x1 tile + lsb are wave-local from here on -> no barrier needed

  f32x4 accg[8];
#pragma unroll
  for (int tt = 0; tt < 8; ++tt) accg[tt] = (f32x4){0.f, 0.f, 0.f, 0.f};
#pragma unroll
  for (int sk = 0; sk < 4; ++sk) {
    BF8 a;
    a.q = *(const uint4*)&sm.tile[wv * 16 + m][sk * 32 + quad * 8];
#pragma unroll
    for (int tt = 0; tt < 8; ++tt) {
      BF8 b;
      b.q = *(const uint4*)(wpack2 + (size_t)((tt * 4 + sk) * 64 + lane) * 8);
      accg[tt] = __builtin_amdgcn_mfma_f32_16x16x32_bf16(a.v, b.v, accg[tt], 0, 0, 0);
    }
  }
  float sc[4];
#pragma unroll
  for (int r = 0; r < 4; ++r) sc[r] = sm.lsb[wv * 16 + quad * 4 + r];
#pragma unroll
  for (int tt = 0; tt < 8; ++tt) {
    const int c = tt * 16 + m;
#pragma unroll
    for (int r = 0; r < 4; ++r)
      sm.tile[wv * 16 + quad * 4 + r][c] = f2bf(accg[tt][r] * sc[r]);
  }
  const int r16 = lane >> 2;
  const int grow = nbase + wv * 16 + r16;
  if (grow < N) {
#pragma unroll
    for (int p = 0; p < 4; ++p) {
      *(uint4*)((char*)msg2 + (size_t)p * planeBytes + (size_t)grow * 64 + sub * 16) =
          *(const uint4*)((const char*)&sm.tile[wv * 16 + r16][0] + p * 64 + sub * 16);
    }
  }
  __syncthreads();  // tile dead before next iteration's pairs staging
}

// ---------------- phase 3: out = act(gather(msg2)), fp32 --------------------
__device__ __forceinline__ void do_gout(SMem& sm, const unsigned short* __restrict__ msg2,
                                        const int* __restrict__ adj,
                                        const float* __restrict__ wgt,
                                        const float* __restrict__ mask,
                                        float* __restrict__ out,
                                        int N, int planeBytes, int nbase) {
  const int lane = threadIdx.x & 63;
  const int wv = threadIdx.x >> 6;
  const int sub = lane & 3;
  const int gnode = nbase + wv * 16 + (lane >> 2);

  f32x2 acc[16];
  gather_core(sm, adj, wgt, msg2, N, planeBytes, nbase, acc);

  const int gcl = gnode < N ? gnode : N - 1;
  const float mm = mask[gcl];
  float s2 = 0.f;
#pragma unroll
  for (int i = 0; i < 16; ++i) {
    acc[i].x *= mm;
    acc[i].y *= mm;
    s2 = fmaf(acc[i].x, acc[i].x, s2);
    s2 = fmaf(acc[i].y, acc[i].y, s2);
  }
  s2 += __shfl_xor(s2, 1);
  s2 += __shfl_xor(s2, 2);
  const float nrm = sqrtf(s2);
  const float ncl = fminf(fmaxf(nrm, EPS), MAX_TANH_ARG);
  const float esc = tanhf(ncl) / fmaxf(nrm, EPS) * mm;
  if (gnode < N) {
#pragma unroll
    for (int p = 0; p < 4; ++p) {
      float4 o0, o1;
      o0.x = fmaxf(esc * acc[p * 4 + 0].x, 0.f) * mm;
      o0.y = fmaxf(esc * acc[p * 4 + 0].y, 0.f) * mm;
      o0.z = fmaxf(esc * acc[p * 4 + 1].x, 0.f) * mm;
      o0.w = fmaxf(esc * acc[p * 4 + 1].y, 0.f) * mm;
      o1.x = fmaxf(esc * acc[p * 4 + 2].x, 0.f) * mm;
      o1.y = fmaxf(esc * acc[p * 4 + 2].y, 0.f) * mm;
      o1.z = fmaxf(esc * acc[p * 4 + 3].x, 0.f) * mm;
      o1.w = fmaxf(esc * acc[p * 4 + 3].y, 0.f) * mm;
      const int cb = p * 32 + sub * 8;
      *(float4*)(out + (size_t)gnode * 128 + cb) = o0;
      *(float4*)(out + (size_t)gnode * 128 + cb + 4) = o1;
    }
  }
  __syncthreads();  // pairs dead before next iteration
}

// ---------------- cooperative single-dispatch path --------------------------
__global__ __launch_bounds__(256, 2) void uber_kernel(
    const float* __restrict__ xf, const int* __restrict__ adj,
    const float* __restrict__ wgt, const float* __restrict__ mask,
    const float* __restrict__ W, unsigned short* __restrict__ wpack,
    unsigned short* __restrict__ msg1, unsigned short* __restrict__ msg2,
    float* __restrict__ out, int N, int gb, int planeBytes) {
  cg::grid_group grid = cg::this_grid();
  __shared__ SMem sm;

  do_pack(W, wpack, blockIdx.x * 256 + threadIdx.x);
  grid.sync();
  for (int tb = blockIdx.x; tb < gb; tb += gridDim.x)
    do_gemm0(sm, xf, mask, wpack, msg1, N, planeBytes, tb);
  grid.sync();
  for (int tb = blockIdx.x; tb < gb; tb += gridDim.x)
    do_fused(sm, msg1, adj, wgt, mask, wpack + 16384, msg2, N, planeBytes, tb * 64);
  grid.sync();
  for (int tb = blockIdx.x; tb < gb; tb += gridDim.x)
    do_gout(sm, msg2, adj, wgt, mask, out, N, planeBytes, tb * 64);
}

// ---------------- fallback multi-dispatch path (same bodies) ----------------
template <int P>
__global__ __launch_bounds__(256, 2) void phase_kernel(
    const float* __restrict__ xf, const int* __restrict__ adj,
    const float* __restrict__ wgt, const float* __restrict__ mask,
    const float* __restrict__ W, unsigned short* __restrict__ wpack,
    unsigned short* __restrict__ msg1, unsigned short* __restrict__ msg2,
    float* __restrict__ out, int N, int gb, int planeBytes) {
  __shared__ SMem sm;
  if (P == 0) {
    do_pack(W, wpack, blockIdx.x * 256 + threadIdx.x);
    return;
  }
  for (int tb = blockIdx.x; tb < gb; tb += gridDim.x) {
    if (P == 1) do_gemm0(sm, xf, mask, wpack, msg1, N, planeBytes, tb);
    if (P == 2) do_fused(sm, msg1, adj, wgt, mask, wpack + 16384, msg2, N, planeBytes, tb * 64);
    if (P == 3) do_gout(sm, msg2, adj, wgt, mask, out, N, planeBytes, tb * 64);
  }
}

extern "C" void kernel_launch(void* const* d_in, const int* in_sizes, int n_in,
                              void* d_out, int out_size, void* d_ws, size_t ws_size,
                              hipStream_t stream) {
  const float* node = (const float*)d_in[0];        // [N,128] fp32
  const int* adj = (const int*)d_in[1];             // [N,32] int32
  const float* wgt = (const float*)d_in[2];         // [N,32] fp32
  const float* mask = (const float*)d_in[3];        // [N,1] fp32
  const float* mw = (const float*)d_in[4];          // [2,128,128] fp32
  float* out = (float*)d_out;
  int N = in_sizes[0] / 128;
  int gb = (N + 63) / 64;
  int planeBytes = gb * 64 * 64;

  unsigned short* wpack = (unsigned short*)d_ws;
  unsigned short* msg2 = (unsigned short*)((char*)d_ws + 65536);
  unsigned short* msg1 = (unsigned short*)d_out;  // dead before phase-3 writes

  void* args[] = {&node, &adj, &wgt, &mask, &mw, &wpack,
                  &msg1, &msg2, &out, &N, &gb, &planeBytes};

  int maxb = 0;
  hipError_t qe = hipOccupancyMaxActiveBlocksPerMultiprocessor(
      &maxb, (const void*)uber_kernel, 256, 0);
  int grid = 256;
  if (qe == hipSuccess && maxb >= 1) {
    long cap = (long)maxb * 256;
    grid = (int)(cap < 512 ? cap : 512);
  }

  hipError_t le = hipLaunchCooperativeKernel((const void*)uber_kernel, dim3(grid),
                                             dim3(256), args, 0, stream);
  if (le != hipSuccess) {
    // Fallback: identical phase bodies, classic stream-ordered dispatches.
    hipLaunchKernelGGL((phase_kernel<0>), dim3(16), dim3(256), 0, stream,
                       node, adj, wgt, mask, mw, wpack, msg1, msg2, out, N, gb, planeBytes);
    hipLaunchKernelGGL((phase_kernel<1>), dim3(gb), dim3(256), 0, stream,
                       node, adj, wgt, mask, mw, wpack, msg1, msg2, out, N, gb, planeBytes);
    hipLaunchKernelGGL((phase_kernel<2>), dim3(gb), dim3(256), 0, stream,
                       node, adj, wgt, mask, mw, wpack, msg1, msg2, out, N, gb, planeBytes);
    hipLaunchKernelGGL((phase_kernel<3>), dim3(gb), dim3(256), 0, stream,
                       node, adj, wgt, mask, mw, wpack, msg1, msg2, out, N, gb, planeBytes);
  }
}

// Round 7
// 210.499 us; speedup vs baseline: 1.5757x; 1.5757x over previous
//
#include <hip/hip_runtime.h>

#define EPS 1e-5f
#define PROJ_EPS 1e-5f
#define MAX_TANH_ARG 15.0f

typedef __bf16 bf16x8 __attribute__((ext_vector_type(8)));
typedef float f32x4 __attribute__((ext_vector_type(4)));
typedef float f32x2 __attribute__((ext_vector_type(2)));

__device__ __forceinline__ unsigned short f2bf(float f) {
  unsigned u = __builtin_bit_cast(unsigned, f);
  u += 0x7fffu + ((u >> 16) & 1u);   // round-to-nearest-even
  return (unsigned short)(u >> 16);
}

union BF8 {
  unsigned short u[8];
  bf16x8 v;
  uint4 q;
};

// ---------------------------------------------------------------------------
// prep: (a) pack W[layer][k][n] -> bf16 MFMA B-frag order;
//       (b) pack edges: u16 id | f16 weight (ids < 50000 < 65536).
// ---------------------------------------------------------------------------
__global__ __launch_bounds__(256) void prep_kernel(
    const float* __restrict__ W, const int* __restrict__ adj,
    const float* __restrict__ wgt, unsigned short* __restrict__ wpack,
    unsigned* __restrict__ edges, int nedge) {
  const int tid = blockIdx.x * 256 + threadIdx.x;
  if (tid < 4096) {
    const int l = tid & 63;
    const int s = (tid >> 6) & 3;
    const int tt = (tid >> 8) & 7;
    const int layer = tid >> 11;
    const int q2 = l >> 4;
    const int n = tt * 16 + (l & 15);
    unsigned short* dst = wpack + ((size_t)((layer * 32 + tt * 4 + s) * 64 + l)) * 8;
    const float* src = W + (size_t)layer * 16384;
#pragma unroll
    for (int j = 0; j < 8; ++j) {
      const int k = s * 32 + q2 * 8 + j;
      dst[j] = f2bf(src[(size_t)k * 128 + n]);
    }
  }
  const int e = tid - 4096;
  if (e >= 0 && e < nedge) {
    const unsigned id = (unsigned)adj[e] & 0xffffu;
    const unsigned short h = __builtin_bit_cast(unsigned short, (_Float16)wgt[e]);
    edges[e] = id | ((unsigned)h << 16);
  }
}

// ---------------------------------------------------------------------------
// gemm0: msg1 planes = mask^2 * (node_repr @ W0). Wave-local LDS A/C tile.
// ---------------------------------------------------------------------------
__global__ __launch_bounds__(256) void gemm0_kernel(
    const float* __restrict__ xf, const float* __restrict__ mask,
    const unsigned short* __restrict__ wpack, unsigned short* __restrict__ msg,
    int N, int planeBytes) {
  __shared__ unsigned short tile[64][136];
  const int lane = threadIdx.x & 63;
  const int wv = threadIdx.x >> 6;
  const int m = lane & 15;
  const int quad = lane >> 4;
  const int wbase = blockIdx.x * 64 + wv * 16;

  {  // coalesced fp32 load -> bf16 stage into own wave's 16 tile rows
    const int r = lane >> 2;
    const int c = (lane & 3) * 32;
    const int gr = wbase + r;
    const int grc = gr < N ? gr : N - 1;
    const float4* src = (const float4*)(xf + (size_t)grc * 128 + c);
    unsigned short* drow = &tile[wv * 16 + r][c];
#pragma unroll
    for (int i = 0; i < 8; ++i) {
      const float4 p = src[i];
      drow[i * 4 + 0] = f2bf(p.x);
      drow[i * 4 + 1] = f2bf(p.y);
      drow[i * 4 + 2] = f2bf(p.z);
      drow[i * 4 + 3] = f2bf(p.w);
    }
  }

  f32x4 acc[8];
#pragma unroll
  for (int tt = 0; tt < 8; ++tt) acc[tt] = (f32x4){0.f, 0.f, 0.f, 0.f};
#pragma unroll
  for (int sk = 0; sk < 4; ++sk) {
    BF8 a;
    a.q = *(const uint4*)&tile[wv * 16 + m][sk * 32 + quad * 8];
#pragma unroll
    for (int tt = 0; tt < 8; ++tt) {
      BF8 b;
      b.q = *(const uint4*)(wpack + (size_t)((tt * 4 + sk) * 64 + lane) * 8);
      acc[tt] = __builtin_amdgcn_mfma_f32_16x16x32_bf16(a.v, b.v, acc[tt], 0, 0, 0);
    }
  }

  float sc[4];
#pragma unroll
  for (int r = 0; r < 4; ++r) {
    int rr = wbase + quad * 4 + r;
    rr = rr < N ? rr : N - 1;
    const float s = mask[rr];
    sc[r] = s * s;
  }
#pragma unroll
  for (int tt = 0; tt < 8; ++tt) {
    const int c = tt * 16 + m;
#pragma unroll
    for (int r = 0; r < 4; ++r)
      tile[wv * 16 + quad * 4 + r][c] = f2bf(acc[tt][r] * sc[r]);
  }
  const int r16 = lane >> 2;
  const int sub2 = lane & 3;
  const int grow = wbase + r16;
  if (grow < N) {
#pragma unroll
    for (int p = 0; p < 4; ++p) {
      *(uint4*)((char*)msg + (size_t)p * planeBytes + (size_t)grow * 64 + sub2 * 16) =
          *(const uint4*)((const char*)&tile[wv * 16 + r16][0] + p * 64 + sub2 * 16);
    }
  }
}

// ---------------------------------------------------------------------------
// gather_plane: block = (tile tb = bid>>2, plane p = bid&3). With round-robin
// blockIdx->XCD, plane p only lands on XCDs {p, p+4} -> per-XCD L2 keeps its
// 3.2 MB plane resident; fabric refill drops ~4x. Decoupled epilogue: store
// relu(c) bf16 per plane + per-(node,plane) partials (sum c^2, sum relu^2);
// the norm-coupled scale chain moves to the consumer kernel.
// ---------------------------------------------------------------------------
__global__ __launch_bounds__(256) void gather_plane_kernel(
    const unsigned short* __restrict__ msg, const unsigned* __restrict__ edges,
    unsigned short* __restrict__ cout, float* __restrict__ scal,
    int N, int planeBytes) {
  __shared__ unsigned ep[64 * 33];  // 8448 B
  const int t = threadIdx.x;
  const int p = blockIdx.x & 3;
  const int nbase = (blockIdx.x >> 2) * 64;

  for (int e = t; e < 64 * 32; e += 256) {
    const int node = e >> 5, k = e & 31;
    const int gn = nbase + node;
    ep[node * 33 + k] = (gn < N) ? edges[(size_t)gn * 32 + k] : 0u;
  }
  __syncthreads();

  const int node = t >> 2;
  const int sub = t & 3;
  const int gnode = nbase + node;
  const unsigned* mp = ep + node * 33;
  const char* plane = (const char*)msg + (size_t)p * planeBytes;
  const int suboff = sub * 16;

  f32x2 acc[4];
#pragma unroll
  for (int d = 0; d < 4; ++d) acc[d] = (f32x2){0.f, 0.f};
#pragma unroll 8
  for (int k = 0; k < 32; ++k) {
    const unsigned pk = mp[k];
    const unsigned id = pk & 0xffffu;
    const float w = (float)__builtin_bit_cast(_Float16, (unsigned short)(pk >> 16));
    const uint4 q = *(const uint4*)(plane + ((size_t)id * 64 + suboff));
    const f32x2 w2 = {w, w};
#pragma unroll
    for (int d = 0; d < 4; ++d) {
      const unsigned qd = (&q.x)[d];
      f32x2 v2;
      v2.x = __builtin_bit_cast(float, qd << 16);
      v2.y = __builtin_bit_cast(float, qd & 0xffff0000u);
      acc[d] = __builtin_elementwise_fma(v2, w2, acc[d]);
    }
  }

  float s_all = 0.f, s_rel = 0.f;
  uint4 pk4;
  unsigned* pw = &pk4.x;
#pragma unroll
  for (int d = 0; d < 4; ++d) {
    s_all = fmaf(acc[d].x, acc[d].x, s_all);
    s_all = fmaf(acc[d].y, acc[d].y, s_all);
    const float r0 = fmaxf(acc[d].x, 0.f);
    const float r1 = fmaxf(acc[d].y, 0.f);
    s_rel = fmaf(r0, r0, s_rel);
    s_rel = fmaf(r1, r1, s_rel);
    pw[d] = (unsigned)f2bf(r0) | ((unsigned)f2bf(r1) << 16);
  }
  s_all += __shfl_xor(s_all, 1);
  s_all += __shfl_xor(s_all, 2);
  s_rel += __shfl_xor(s_rel, 1);
  s_rel += __shfl_xor(s_rel, 2);

  if (gnode < N) {
    *(uint4*)((char*)cout + (size_t)p * planeBytes + (size_t)gnode * 64 + suboff) = pk4;
    if (sub == 0)
      *(float2*)(scal + (size_t)gnode * 8 + p * 2) = make_float2(s_all, s_rel);
  }
}

// ---------------------------------------------------------------------------
// gemm1: msg2 planes = rs * (relu(c1) @ W1), rs = ls*mm^2*f1 computed inline
// from the per-plane partials (f1 = esc*mm^3; x1 = f1*relu(c1)).
// A-frags read directly from cA planes (bf16, already relu'd).
// ---------------------------------------------------------------------------
__global__ __launch_bounds__(256) void gemm1_kernel(
    const unsigned short* __restrict__ cA, const float* __restrict__ scalA,
    const float* __restrict__ mask, const unsigned short* __restrict__ wpack2,
    unsigned short* __restrict__ msg, int N, int planeBytes) {
  __shared__ unsigned short tile[64][136];
  const int lane = threadIdx.x & 63;
  const int wv = threadIdx.x >> 6;
  const int m = lane & 15;
  const int quad = lane >> 4;
  const int wbase = blockIdx.x * 64 + wv * 16;
  const int row = wbase + m;
  const int rowc = row < N ? row : N - 1;

  f32x4 acc[8];
#pragma unroll
  for (int tt = 0; tt < 8; ++tt) acc[tt] = (f32x4){0.f, 0.f, 0.f, 0.f};
#pragma unroll
  for (int sk = 0; sk < 4; ++sk) {
    BF8 a;
    a.q = *(const uint4*)((const char*)cA + (size_t)sk * planeBytes +
                          (size_t)rowc * 64 + quad * 16);
#pragma unroll
    for (int tt = 0; tt < 8; ++tt) {
      BF8 b;
      b.q = *(const uint4*)(wpack2 + (size_t)((tt * 4 + sk) * 64 + lane) * 8);
      acc[tt] = __builtin_amdgcn_mfma_f32_16x16x32_bf16(a.v, b.v, acc[tt], 0, 0, 0);
    }
  }

  float sc[4];
#pragma unroll
  for (int r = 0; r < 4; ++r) {
    int rr = wbase + quad * 4 + r;
    rr = rr < N ? rr : N - 1;
    const float* s8 = scalA + (size_t)rr * 8;
    const float S_all = s8[0] + s8[2] + s8[4] + s8[6];
    const float S_rel = s8[1] + s8[3] + s8[5] + s8[7];
    const float mm = mask[rr];
    const float s2 = mm * mm * S_all;
    const float nrm = sqrtf(s2);
    const float ncl = fminf(fmaxf(nrm, EPS), MAX_TANH_ARG);
    const float f1 = tanhf(ncl) / fmaxf(nrm, EPS) * mm * mm * mm;  // x1 = f1*relu(c1)
    const float r2 = f1 * f1 * S_rel;
    const float nr = sqrtf(r2);
    const float nc2 = fminf(fmaxf(nr, EPS), 1.0f - PROJ_EPS);
    const float ls = 0.5f * logf((1.f + nc2) / (1.f - nc2)) / fmaxf(nr, EPS);
    sc[r] = ls * mm * mm * f1;
  }
#pragma unroll
  for (int tt = 0; tt < 8; ++tt) {
    const int c = tt * 16 + m;
#pragma unroll
    for (int r = 0; r < 4; ++r)
      tile[wv * 16 + quad * 4 + r][c] = f2bf(acc[tt][r] * sc[r]);
  }
  const int r16 = lane >> 2;
  const int sub2 = lane & 3;
  const int grow = wbase + r16;
  if (grow < N) {
#pragma unroll
    for (int p = 0; p < 4; ++p) {
      *(uint4*)((char*)msg + (size_t)p * planeBytes + (size_t)grow * 64 + sub2 * 16) =
          *(const uint4*)((const char*)&tile[wv * 16 + r16][0] + p * 64 + sub2 * 16);
    }
  }
}

// ---------------------------------------------------------------------------
// final: out = f2 * relu(c2), f2 = tanh(clip(|c2*m|))/|..| * m^3, fp32 stores.
// ---------------------------------------------------------------------------
__global__ __launch_bounds__(256) void final_kernel(
    const unsigned short* __restrict__ cB, const float* __restrict__ scalB,
    const float* __restrict__ mask, float* __restrict__ out,
    int N, int planeBytes) {
  const int t = threadIdx.x;
  const int node = t >> 2;
  const int sub = t & 3;
  const int gnode = blockIdx.x * 64 + node;
  if (gnode >= N) return;
  const float* s8 = scalB + (size_t)gnode * 8;
  const float S_all = s8[0] + s8[2] + s8[4] + s8[6];
  const float mm = mask[gnode];
  const float s2 = mm * mm * S_all;
  const float nrm = sqrtf(s2);
  const float ncl = fminf(fmaxf(nrm, EPS), MAX_TANH_ARG);
  const float f2 = tanhf(ncl) / fmaxf(nrm, EPS) * mm * mm * mm;
#pragma unroll
  for (int p = 0; p < 4; ++p) {
    const uint4 q = *(const uint4*)((const char*)cB + (size_t)p * planeBytes +
                                    (size_t)gnode * 64 + sub * 16);
    float4 o0, o1;
    o0.x = f2 * __builtin_bit_cast(float, q.x << 16);
    o0.y = f2 * __builtin_bit_cast(float, q.x & 0xffff0000u);
    o0.z = f2 * __builtin_bit_cast(float, q.y << 16);
    o0.w = f2 * __builtin_bit_cast(float, q.y & 0xffff0000u);
    o1.x = f2 * __builtin_bit_cast(float, q.z << 16);
    o1.y = f2 * __builtin_bit_cast(float, q.z & 0xffff0000u);
    o1.z = f2 * __builtin_bit_cast(float, q.w << 16);
    o1.w = f2 * __builtin_bit_cast(float, q.w & 0xffff0000u);
    const int cb = p * 32 + sub * 8;
    *(float4*)(out + (size_t)gnode * 128 + cb) = o0;
    *(float4*)(out + (size_t)gnode * 128 + cb + 4) = o1;
  }
}

extern "C" void kernel_launch(void* const* d_in, const int* in_sizes, int n_in,
                              void* d_out, int out_size, void* d_ws, size_t ws_size,
                              hipStream_t stream) {
  const float* node = (const float*)d_in[0];        // [N,128] fp32
  const int* adj = (const int*)d_in[1];             // [N,32] int32
  const float* wgt = (const float*)d_in[2];         // [N,32] fp32
  const float* mask = (const float*)d_in[3];        // [N,1] fp32
  const float* mw = (const float*)d_in[4];          // [2,128,128] fp32
  float* out = (float*)d_out;
  const int N = in_sizes[0] / 128;
  const int gb = (N + 63) / 64;
  const int planeBytes = gb * 64 * 64;
  const int nedge = N * 32;

  // d_out scratch: [0,4*pB) msg planes (msg1 then msg2) | edges (4B*nedge) |
  //                scalarsA (N*32 B). All dead before final_kernel's writes.
  unsigned short* msg = (unsigned short*)d_out;
  unsigned* edges = (unsigned*)((char*)d_out + (size_t)4 * planeBytes);
  float* scalA = (float*)((char*)d_out + (size_t)4 * planeBytes + (size_t)nedge * 4);
  // ws: wpack 64 KiB | cA/cB planes (4*pB, reused) | scalarsB (N*32 B)
  unsigned short* wpack = (unsigned short*)d_ws;
  unsigned short* cAB = (unsigned short*)((char*)d_ws + 65536);
  float* scalB = (float*)((char*)d_ws + 65536 + (size_t)4 * planeBytes);

  hipLaunchKernelGGL(prep_kernel, dim3((4096 + nedge + 255) / 256), dim3(256), 0,
                     stream, mw, adj, wgt, wpack, edges, nedge);
  hipLaunchKernelGGL(gemm0_kernel, dim3(gb), dim3(256), 0, stream,
                     node, mask, wpack, msg, N, planeBytes);
  hipLaunchKernelGGL(gather_plane_kernel, dim3(gb * 4), dim3(256), 0, stream,
                     msg, edges, cAB, scalA, N, planeBytes);
  hipLaunchKernelGGL(gemm1_kernel, dim3(gb), dim3(256), 0, stream,
                     cAB, scalA, mask, wpack + 16384, msg, N, planeBytes);
  hipLaunchKernelGGL(gather_plane_kernel, dim3(gb * 4), dim3(256), 0, stream,
                     msg, edges, cAB, scalB, N, planeBytes);
  hipLaunchKernelGGL(final_kernel, dim3(gb), dim3(256), 0, stream,
                     cAB, scalB, mask, out, N, planeBytes);
}

// Round 8
// 198.288 us; speedup vs baseline: 1.6727x; 1.0616x over previous
//
#include <hip/hip_runtime.h>

#define EPS 1e-5f
#define PROJ_EPS 1e-5f
#define MAX_TANH_ARG 15.0f

typedef __bf16 bf16x8 __attribute__((ext_vector_type(8)));
typedef float f32x4 __attribute__((ext_vector_type(4)));
typedef float f32x2 __attribute__((ext_vector_type(2)));

__device__ __forceinline__ unsigned short f2bf(float f) {
  unsigned u = __builtin_bit_cast(unsigned, f);
  u += 0x7fffu + ((u >> 16) & 1u);   // round-to-nearest-even
  return (unsigned short)(u >> 16);
}

union BF8 {
  unsigned short u[8];
  bf16x8 v;
  uint4 q;
};

// ---------------------------------------------------------------------------
// prep: (a) pack W[layer][k][n] -> bf16 MFMA B-frag order;
//       (b) pack edges: u16 id | f16 weight (ids < 50000 < 65536).
// ---------------------------------------------------------------------------
__global__ __launch_bounds__(256) void prep_kernel(
    const float* __restrict__ W, const int* __restrict__ adj,
    const float* __restrict__ wgt, unsigned short* __restrict__ wpack,
    unsigned* __restrict__ edges, int nedge) {
  const int tid = blockIdx.x * 256 + threadIdx.x;
  if (tid < 4096) {
    const int l = tid & 63;
    const int s = (tid >> 6) & 3;
    const int tt = (tid >> 8) & 7;
    const int layer = tid >> 11;
    const int q2 = l >> 4;
    const int n = tt * 16 + (l & 15);
    unsigned short* dst = wpack + ((size_t)((layer * 32 + tt * 4 + s) * 64 + l)) * 8;
    const float* src = W + (size_t)layer * 16384;
#pragma unroll
    for (int j = 0; j < 8; ++j) {
      const int k = s * 32 + q2 * 8 + j;
      dst[j] = f2bf(src[(size_t)k * 128 + n]);
    }
  }
  const int e = tid - 4096;
  if (e >= 0 && e < nedge) {
    const unsigned id = (unsigned)adj[e] & 0xffffu;
    const unsigned short h = __builtin_bit_cast(unsigned short, (_Float16)wgt[e]);
    edges[e] = id | ((unsigned)h << 16);
  }
}

// ---------------------------------------------------------------------------
// gemm0: msg1 planes = mask^2 * (node_repr @ W0). Wave-local LDS A/C tile.
// ---------------------------------------------------------------------------
__global__ __launch_bounds__(256) void gemm0_kernel(
    const float* __restrict__ xf, const float* __restrict__ mask,
    const unsigned short* __restrict__ wpack, unsigned short* __restrict__ msg,
    int N, int planeBytes) {
  __shared__ unsigned short tile[64][136];
  const int lane = threadIdx.x & 63;
  const int wv = threadIdx.x >> 6;
  const int m = lane & 15;
  const int quad = lane >> 4;
  const int wbase = blockIdx.x * 64 + wv * 16;

  {  // coalesced fp32 load -> bf16 stage into own wave's 16 tile rows
    const int r = lane >> 2;
    const int c = (lane & 3) * 32;
    const int gr = wbase + r;
    const int grc = gr < N ? gr : N - 1;
    const float4* src = (const float4*)(xf + (size_t)grc * 128 + c);
    unsigned short* drow = &tile[wv * 16 + r][c];
#pragma unroll
    for (int i = 0; i < 8; ++i) {
      const float4 p = src[i];
      drow[i * 4 + 0] = f2bf(p.x);
      drow[i * 4 + 1] = f2bf(p.y);
      drow[i * 4 + 2] = f2bf(p.z);
      drow[i * 4 + 3] = f2bf(p.w);
    }
  }

  f32x4 acc[8];
#pragma unroll
  for (int tt = 0; tt < 8; ++tt) acc[tt] = (f32x4){0.f, 0.f, 0.f, 0.f};
#pragma unroll
  for (int sk = 0; sk < 4; ++sk) {
    BF8 a;
    a.q = *(const uint4*)&tile[wv * 16 + m][sk * 32 + quad * 8];
#pragma unroll
    for (int tt = 0; tt < 8; ++tt) {
      BF8 b;
      b.q = *(const uint4*)(wpack + (size_t)((tt * 4 + sk) * 64 + lane) * 8);
      acc[tt] = __builtin_amdgcn_mfma_f32_16x16x32_bf16(a.v, b.v, acc[tt], 0, 0, 0);
    }
  }

  float sc[4];
#pragma unroll
  for (int r = 0; r < 4; ++r) {
    int rr = wbase + quad * 4 + r;
    rr = rr < N ? rr : N - 1;
    const float s = mask[rr];
    sc[r] = s * s;
  }
#pragma unroll
  for (int tt = 0; tt < 8; ++tt) {
    const int c = tt * 16 + m;
#pragma unroll
    for (int r = 0; r < 4; ++r)
      tile[wv * 16 + quad * 4 + r][c] = f2bf(acc[tt][r] * sc[r]);
  }
  const int r16 = lane >> 2;
  const int sub2 = lane & 3;
  const int grow = wbase + r16;
  if (grow < N) {
#pragma unroll
    for (int p = 0; p < 4; ++p) {
      *(uint4*)((char*)msg + (size_t)p * planeBytes + (size_t)grow * 64 + sub2 * 16) =
          *(const uint4*)((const char*)&tile[wv * 16 + r16][0] + p * 64 + sub2 * 16);
    }
  }
}

// ---------------------------------------------------------------------------
// gather_plane: block = (tile = bid>>2, plane p = bid&3); XCD-affine planes.
// MLP-boosted: all 32 edge words preloaded to registers; explicit 2-stage
// software pipeline (8 uint4 gathers in flight while consuming previous 8).
// __launch_bounds__(256,4) lifts the VGPR cap (R7's 16-VGPR build serialized
// the k-loop on L2 latency). Epilogue stores relu(c) bf16 + per-plane
// partials (sum c^2, sum relu^2); scale chain moves to the consumer.
// ---------------------------------------------------------------------------
__global__ __launch_bounds__(256, 4) void gather_plane_kernel(
    const unsigned short* __restrict__ msg, const unsigned* __restrict__ edges,
    unsigned short* __restrict__ cout, float* __restrict__ scal,
    int N, int planeBytes) {
  __shared__ unsigned ep[64 * 36];  // stride 36 words: 16B-aligned rows
  const int t = threadIdx.x;
  const int p = blockIdx.x & 3;
  const int nbase = (blockIdx.x >> 2) * 64;

  for (int e = t; e < 64 * 32; e += 256) {
    const int node = e >> 5, k = e & 31;
    const int gn = nbase + node;
    ep[node * 36 + k] = (gn < N) ? edges[(size_t)gn * 32 + k] : 0u;
  }
  __syncthreads();

  const int node = t >> 2;
  const int sub = t & 3;
  const int gnode = nbase + node;
  const unsigned* mp = ep + node * 36;
  const char* plane = (const char*)msg + (size_t)p * planeBytes;
  const int suboff = sub * 16;

  unsigned ew[32];
#pragma unroll
  for (int i = 0; i < 8; ++i)
    *(uint4*)&ew[4 * i] = *(const uint4*)(mp + 4 * i);

  f32x2 acc[4];
#pragma unroll
  for (int d = 0; d < 4; ++d) acc[d] = (f32x2){0.f, 0.f};

  uint4 q[8], q2[8];
#pragma unroll
  for (int k = 0; k < 8; ++k)
    q[k] = *(const uint4*)(plane + ((size_t)(ew[k] & 0xffffu) * 64 + suboff));

#pragma unroll
  for (int b = 0; b < 4; ++b) {
    if (b < 3) {
#pragma unroll
      for (int k = 0; k < 8; ++k)
        q2[k] = *(const uint4*)(plane +
                                ((size_t)(ew[8 * (b + 1) + k] & 0xffffu) * 64 + suboff));
    }
#pragma unroll
    for (int k = 0; k < 8; ++k) {
      const float w = (float)__builtin_bit_cast(
          _Float16, (unsigned short)(ew[8 * b + k] >> 16));
      const f32x2 w2 = {w, w};
#pragma unroll
      for (int d = 0; d < 4; ++d) {
        const unsigned qd = (&q[k].x)[d];
        f32x2 v2;
        v2.x = __builtin_bit_cast(float, qd << 16);
        v2.y = __builtin_bit_cast(float, qd & 0xffff0000u);
        acc[d] = __builtin_elementwise_fma(v2, w2, acc[d]);
      }
    }
    if (b < 3) {
#pragma unroll
      for (int k = 0; k < 8; ++k) q[k] = q2[k];
    }
  }

  float s_all = 0.f, s_rel = 0.f;
  uint4 pk4;
  unsigned* pw = &pk4.x;
#pragma unroll
  for (int d = 0; d < 4; ++d) {
    s_all = fmaf(acc[d].x, acc[d].x, s_all);
    s_all = fmaf(acc[d].y, acc[d].y, s_all);
    const float r0 = fmaxf(acc[d].x, 0.f);
    const float r1 = fmaxf(acc[d].y, 0.f);
    s_rel = fmaf(r0, r0, s_rel);
    s_rel = fmaf(r1, r1, s_rel);
    pw[d] = (unsigned)f2bf(r0) | ((unsigned)f2bf(r1) << 16);
  }
  s_all += __shfl_xor(s_all, 1);
  s_all += __shfl_xor(s_all, 2);
  s_rel += __shfl_xor(s_rel, 1);
  s_rel += __shfl_xor(s_rel, 2);

  if (gnode < N) {
    *(uint4*)((char*)cout + (size_t)p * planeBytes + (size_t)gnode * 64 + suboff) = pk4;
    if (sub == 0)
      *(float2*)(scal + (size_t)gnode * 8 + p * 2) = make_float2(s_all, s_rel);
  }
}

// ---------------------------------------------------------------------------
// gemm1: msg2 planes = rs * (relu(c1) @ W1), rs = ls*mm^2*f1 computed inline
// from the per-plane partials (f1 = esc*mm^3; x1 = f1*relu(c1)).
// ---------------------------------------------------------------------------
__global__ __launch_bounds__(256) void gemm1_kernel(
    const unsigned short* __restrict__ cA, const float* __restrict__ scalA,
    const float* __restrict__ mask, const unsigned short* __restrict__ wpack2,
    unsigned short* __restrict__ msg, int N, int planeBytes) {
  __shared__ unsigned short tile[64][136];
  const int lane = threadIdx.x & 63;
  const int wv = threadIdx.x >> 6;
  const int m = lane & 15;
  const int quad = lane >> 4;
  const int wbase = blockIdx.x * 64 + wv * 16;
  const int row = wbase + m;
  const int rowc = row < N ? row : N - 1;

  f32x4 acc[8];
#pragma unroll
  for (int tt = 0; tt < 8; ++tt) acc[tt] = (f32x4){0.f, 0.f, 0.f, 0.f};
#pragma unroll
  for (int sk = 0; sk < 4; ++sk) {
    BF8 a;
    a.q = *(const uint4*)((const char*)cA + (size_t)sk * planeBytes +
                          (size_t)rowc * 64 + quad * 16);
#pragma unroll
    for (int tt = 0; tt < 8; ++tt) {
      BF8 b;
      b.q = *(const uint4*)(wpack2 + (size_t)((tt * 4 + sk) * 64 + lane) * 8);
      acc[tt] = __builtin_amdgcn_mfma_f32_16x16x32_bf16(a.v, b.v, acc[tt], 0, 0, 0);
    }
  }

  float sc[4];
#pragma unroll
  for (int r = 0; r < 4; ++r) {
    int rr = wbase + quad * 4 + r;
    rr = rr < N ? rr : N - 1;
    const float* s8 = scalA + (size_t)rr * 8;
    const float S_all = s8[0] + s8[2] + s8[4] + s8[6];
    const float S_rel = s8[1] + s8[3] + s8[5] + s8[7];
    const float mm = mask[rr];
    const float s2 = mm * mm * S_all;
    const float nrm = sqrtf(s2);
    const float ncl = fminf(fmaxf(nrm, EPS), MAX_TANH_ARG);
    const float f1 = tanhf(ncl) / fmaxf(nrm, EPS) * mm * mm * mm;  // x1 = f1*relu(c1)
    const float r2 = f1 * f1 * S_rel;
    const float nr = sqrtf(r2);
    const float nc2 = fminf(fmaxf(nr, EPS), 1.0f - PROJ_EPS);
    const float ls = 0.5f * logf((1.f + nc2) / (1.f - nc2)) / fmaxf(nr, EPS);
    sc[r] = ls * mm * mm * f1;
  }
#pragma unroll
  for (int tt = 0; tt < 8; ++tt) {
    const int c = tt * 16 + m;
#pragma unroll
    for (int r = 0; r < 4; ++r)
      tile[wv * 16 + quad * 4 + r][c] = f2bf(acc[tt][r] * sc[r]);
  }
  const int r16 = lane >> 2;
  const int sub2 = lane & 3;
  const int grow = wbase + r16;
  if (grow < N) {
#pragma unroll
    for (int p = 0; p < 4; ++p) {
      *(uint4*)((char*)msg + (size_t)p * planeBytes + (size_t)grow * 64 + sub2 * 16) =
          *(const uint4*)((const char*)&tile[wv * 16 + r16][0] + p * 64 + sub2 * 16);
    }
  }
}

// ---------------------------------------------------------------------------
// final: out = f2 * relu(c2), f2 = tanh(clip(|c2*m|))/|..| * m^3, fp32 stores.
// ---------------------------------------------------------------------------
__global__ __launch_bounds__(256) void final_kernel(
    const unsigned short* __restrict__ cB, const float* __restrict__ scalB,
    const float* __restrict__ mask, float* __restrict__ out,
    int N, int planeBytes) {
  const int t = threadIdx.x;
  const int node = t >> 2;
  const int sub = t & 3;
  const int gnode = blockIdx.x * 64 + node;
  if (gnode >= N) return;
  const float* s8 = scalB + (size_t)gnode * 8;
  const float S_all = s8[0] + s8[2] + s8[4] + s8[6];
  const float mm = mask[gnode];
  const float s2 = mm * mm * S_all;
  const float nrm = sqrtf(s2);
  const float ncl = fminf(fmaxf(nrm, EPS), MAX_TANH_ARG);
  const float f2 = tanhf(ncl) / fmaxf(nrm, EPS) * mm * mm * mm;
#pragma unroll
  for (int p = 0; p < 4; ++p) {
    const uint4 q = *(const uint4*)((const char*)cB + (size_t)p * planeBytes +
                                    (size_t)gnode * 64 + sub * 16);
    float4 o0, o1;
    o0.x = f2 * __builtin_bit_cast(float, q.x << 16);
    o0.y = f2 * __builtin_bit_cast(float, q.x & 0xffff0000u);
    o0.z = f2 * __builtin_bit_cast(float, q.y << 16);
    o0.w = f2 * __builtin_bit_cast(float, q.y & 0xffff0000u);
    o1.x = f2 * __builtin_bit_cast(float, q.z << 16);
    o1.y = f2 * __builtin_bit_cast(float, q.z & 0xffff0000u);
    o1.z = f2 * __builtin_bit_cast(float, q.w << 16);
    o1.w = f2 * __builtin_bit_cast(float, q.w & 0xffff0000u);
    const int cb = p * 32 + sub * 8;
    *(float4*)(out + (size_t)gnode * 128 + cb) = o0;
    *(float4*)(out + (size_t)gnode * 128 + cb + 4) = o1;
  }
}

extern "C" void kernel_launch(void* const* d_in, const int* in_sizes, int n_in,
                              void* d_out, int out_size, void* d_ws, size_t ws_size,
                              hipStream_t stream) {
  const float* node = (const float*)d_in[0];        // [N,128] fp32
  const int* adj = (const int*)d_in[1];             // [N,32] int32
  const float* wgt = (const float*)d_in[2];         // [N,32] fp32
  const float* mask = (const float*)d_in[3];        // [N,1] fp32
  const float* mw = (const float*)d_in[4];          // [2,128,128] fp32
  float* out = (float*)d_out;
  const int N = in_sizes[0] / 128;
  const int gb = (N + 63) / 64;
  const int planeBytes = gb * 64 * 64;
  const int nedge = N * 32;

  // d_out scratch: [0,4*pB) msg planes (msg1 then msg2) | edges (4B*nedge) |
  //                scalarsA (N*32 B). All dead before final_kernel's writes.
  unsigned short* msg = (unsigned short*)d_out;
  unsigned* edges = (unsigned*)((char*)d_out + (size_t)4 * planeBytes);
  float* scalA = (float*)((char*)d_out + (size_t)4 * planeBytes + (size_t)nedge * 4);
  // ws: wpack 64 KiB | cA/cB planes (4*pB, reused) | scalarsB (N*32 B)
  unsigned short* wpack = (unsigned short*)d_ws;
  unsigned short* cAB = (unsigned short*)((char*)d_ws + 65536);
  float* scalB = (float*)((char*)d_ws + 65536 + (size_t)4 * planeBytes);

  hipLaunchKernelGGL(prep_kernel, dim3((4096 + nedge + 255) / 256), dim3(256), 0,
                     stream, mw, adj, wgt, wpack, edges, nedge);
  hipLaunchKernelGGL(gemm0_kernel, dim3(gb), dim3(256), 0, stream,
                     node, mask, wpack, msg, N, planeBytes);
  hipLaunchKernelGGL(gather_plane_kernel, dim3(gb * 4), dim3(256), 0, stream,
                     msg, edges, cAB, scalA, N, planeBytes);
  hipLaunchKernelGGL(gemm1_kernel, dim3(gb), dim3(256), 0, stream,
                     cAB, scalA, mask, wpack + 16384, msg, N, planeBytes);
  hipLaunchKernelGGL(gather_plane_kernel, dim3(gb * 4), dim3(256), 0, stream,
                     msg, edges, cAB, scalB, N, planeBytes);
  hipLaunchKernelGGL(final_kernel, dim3(gb), dim3(256), 0, stream,
                     cAB, scalB, mask, out, N, planeBytes);
}